// Round 1
// baseline (527.590 us; speedup 1.0000x reference)
//
#include <hip/hip_runtime.h>
#include <hip/hip_bf16.h>
#include <math.h>

#define NB_B 256
#define NB_S 50
#define NB_NB 8
#define NB_D 128
#define NB_NITEMS 100000

__device__ __forceinline__ float wave_sum(float t) {
#pragma unroll
  for (int off = 32; off; off >>= 1) t += __shfl_xor(t, off);
  return t;
}

__device__ __forceinline__ float sigf(float x) { return 1.f / (1.f + __expf(-x)); }

// ---------------- hop aggregation: X = self + sum_k alpha_k * nb_k ----------------
// LEVEL 0: pairs p in [0,102400): p=(b,m), m=s*8+j; e_self=adj_e[h[b,s]*8+j]; nb from item_emb[adj_e[e_self]]
// LEVEL 1: pairs p in [0,12800):  p=(b,s); e_self=h[b,s]; nb from NEIB[(p*8+k)]
template <int LEVEL>
__global__ __launch_bounds__(256) void hop_x_kernel(
    const int* __restrict__ h_iids, const int* __restrict__ adj_e,
    const int* __restrict__ adj_r, const float* __restrict__ item_emb,
    const float* __restrict__ rel_emb, const float* __restrict__ neib,
    const float* __restrict__ Wa, float* __restrict__ Xout, int npairs) {
  int p = (int)((blockIdx.x * blockDim.x + threadIdx.x) >> 6);
  p = __builtin_amdgcn_readfirstlane(p);
  int ln = threadIdx.x & 63;
  if (p >= npairs) return;

  int e_self;
  if (LEVEL == 0) {
    int b = p / (NB_S * NB_NB);
    int m = p % (NB_S * NB_NB);
    int s = m >> 3, j = m & 7;
    int h = h_iids[b * NB_S + s];
    e_self = adj_e[h * NB_NB + j];
  } else {
    e_self = h_iids[p];  // p = b*S + s
  }

  float wa0 = Wa[ln], wa1 = Wa[64 + ln];
  const float* selfp = item_emb + (size_t)e_self * NB_D;
  float s0 = selfp[ln], s1 = selfp[64 + ln];

  float nb0[NB_NB], nb1[NB_NB], att[NB_NB];
#pragma unroll
  for (int k = 0; k < NB_NB; k++) {
    int r = adj_r[e_self * NB_NB + k];
    const float* nbp;
    if (LEVEL == 0) {
      int e2 = adj_e[e_self * NB_NB + k];
      nbp = item_emb + (size_t)e2 * NB_D;
    } else {
      nbp = neib + ((size_t)p * NB_NB + k) * NB_D;
    }
    nb0[k] = nbp[ln];
    nb1[k] = nbp[64 + ln];
    const float* rp = rel_emb + (size_t)r * NB_D;
    float t = s0 * rp[ln] * nb0[k] * wa0 + s1 * rp[64 + ln] * nb1[k] * wa1;
    att[k] = wave_sum(t);  // +ba omitted: softmax-invariant constant
  }
  float mx = att[0];
#pragma unroll
  for (int k = 1; k < NB_NB; k++) mx = fmaxf(mx, att[k]);
  float den = 0.f, ex[NB_NB];
#pragma unroll
  for (int k = 0; k < NB_NB; k++) { ex[k] = __expf(att[k] - mx); den += ex[k]; }
  float inv = 1.f / den;
  float x0 = s0, x1 = s1;
#pragma unroll
  for (int k = 0; k < NB_NB; k++) {
    float a = ex[k] * inv;
    x0 += a * nb0[k];
    x1 += a * nb1[k];
  }
  float* o = Xout + (size_t)p * NB_D;
  o[ln] = x0;
  o[64 + ln] = x1;
}

// ---------------- generic Y[N,CO] = X[N,128] @ W[128,CO] + bias ----------------
// One wave handles RPW rows; rows are wave-uniform so X loads become s_load.
// In-place safe (X==Y): each wave reads only the rows it later writes.
template <int CO, int RPW>
__global__ __launch_bounds__(256) void lin_kernel(const float* X,
                                                  const float* __restrict__ W,
                                                  const float* __restrict__ bias,
                                                  float* Y, int nrows) {
  constexpr int Q = CO / 64;
  int wave = (int)(blockIdx.x * 4 + (threadIdx.x >> 6));
  int ln = threadIdx.x & 63;
  int row0 = __builtin_amdgcn_readfirstlane(wave) * RPW;
  if (row0 >= nrows) return;

  float acc[RPW][Q];
#pragma unroll
  for (int r = 0; r < RPW; r++)
#pragma unroll
    for (int q = 0; q < Q; q++) acc[r][q] = 0.f;

  for (int d0 = 0; d0 < 128; d0 += 4) {
    float xv[RPW][4];
#pragma unroll
    for (int r = 0; r < RPW; r++)
#pragma unroll
      for (int dd = 0; dd < 4; dd++)
        xv[r][dd] = X[(size_t)(row0 + r) * 128 + d0 + dd];  // uniform -> s_load
#pragma unroll
    for (int dd = 0; dd < 4; dd++) {
      float w[Q];
#pragma unroll
      for (int q = 0; q < Q; q++) w[q] = W[(size_t)(d0 + dd) * CO + q * 64 + ln];
#pragma unroll
      for (int r = 0; r < RPW; r++)
#pragma unroll
        for (int q = 0; q < Q; q++) acc[r][q] += xv[r][dd] * w[q];
    }
  }
#pragma unroll
  for (int q = 0; q < Q; q++) {
    float bv = bias[q * 64 + ln];
#pragma unroll
    for (int r = 0; r < RPW; r++)
      Y[(size_t)(row0 + r) * CO + q * 64 + ln] = acc[r][q] + bv;
  }
}

// ---------------- GRU: one block per batch element, Whh column in VGPRs ----------------
__global__ __launch_bounds__(384) void gru_kernel(const float* __restrict__ GI,
                                                  const float* __restrict__ Whh,
                                                  const float* __restrict__ bhh,
                                                  float* __restrict__ OUT) {
  int b = blockIdx.x;
  int j = threadIdx.x;  // 0..383
  __shared__ float h_s[128];
  __shared__ float gh_s[384];

  float wcol[128];
#pragma unroll
  for (int d = 0; d < 128; d++) wcol[d] = Whh[(size_t)d * 384 + j];
  float bh = bhh[j];
  if (j < 128) h_s[j] = 0.f;
  __syncthreads();

  for (int t = 0; t < NB_S; t++) {
    float gh = bh;
    const float4* h4 = (const float4*)h_s;
#pragma unroll
    for (int d4 = 0; d4 < 32; d4++) {
      float4 hv = h4[d4];
      gh += hv.x * wcol[4 * d4] + hv.y * wcol[4 * d4 + 1] +
            hv.z * wcol[4 * d4 + 2] + hv.w * wcol[4 * d4 + 3];
    }
    gh_s[j] = gh;
    __syncthreads();
    if (j < 128) {
      const float* gi = GI + ((size_t)b * NB_S + t) * 384;
      float r = sigf(gi[j] + gh_s[j]);
      float z = sigf(gi[128 + j] + gh_s[128 + j]);
      float n = tanhf(gi[256 + j] + r * gh_s[256 + j]);
      float h2 = (1.f - z) * n + z * h_s[j];
      OUT[((size_t)b * NB_S + t) * 128 + j] = h2;
      h_s[j] = h2;  // own-index RAW only; other readers passed the barrier above
    }
    __syncthreads();
  }
}

// ---------------- pooling ----------------
__global__ __launch_bounds__(128) void pool_a_kernel(
    const int* __restrict__ h_iids, const float* __restrict__ OUT,
    const float* __restrict__ W1, const float* __restrict__ b1,
    float* __restrict__ LOCAL, float* __restrict__ Q1) {
  int b = blockIdx.x, c = threadIdx.x;
  int cnt = 0;
  for (int s = 0; s < NB_S; s++) cnt += (h_iids[b * NB_S + s] != 0);
  int li = min(max(cnt - 1, 0), NB_S - 1);
  __shared__ float lh[128];
  float lv = OUT[((size_t)b * NB_S + li) * 128 + c];
  lh[c] = lv;
  LOCAL[b * 128 + c] = lv;
  __syncthreads();
  float acc = b1[c];
  for (int d = 0; d < 128; d++) acc += lh[d] * W1[(size_t)d * 128 + c];
  Q1[b * 128 + c] = acc;
}

__global__ __launch_bounds__(256) void pool_b_kernel(
    const float* __restrict__ OUT, const float* __restrict__ W2,
    const float* __restrict__ b2, const float* __restrict__ W3,
    const float* __restrict__ Q1, float* __restrict__ AL) {
  int p = (int)((blockIdx.x * blockDim.x + threadIdx.x) >> 6);
  p = __builtin_amdgcn_readfirstlane(p);
  int ln = threadIdx.x & 63;
  if (p >= NB_B * NB_S) return;
  int b = p / NB_S;
  const float* x = OUT + (size_t)p * 128;
  float acc0 = b2[ln], acc1 = b2[64 + ln];
  for (int d = 0; d < 128; d++) {
    float xv = x[d];  // uniform -> s_load
    acc0 += xv * W2[(size_t)d * 128 + ln];
    acc1 += xv * W2[(size_t)d * 128 + 64 + ln];
  }
  float t = sigf(Q1[b * 128 + ln] + acc0) * W3[ln] +
            sigf(Q1[b * 128 + 64 + ln] + acc1) * W3[64 + ln];
  t = wave_sum(t);
  if (ln == 0) AL[p] = t;
}

__global__ __launch_bounds__(128) void pool_c_kernel(
    const float* __restrict__ OUT, const float* __restrict__ AL,
    const float* __restrict__ LOCAL, const float* __restrict__ Wtr,
    const float* __restrict__ btr, float* __restrict__ GHT) {
  int b = blockIdx.x, d = threadIdx.x;
  float g = 0.f;
  for (int s = 0; s < NB_S; s++)
    g += AL[b * NB_S + s] * OUT[((size_t)b * NB_S + s) * 128 + d];
  __shared__ float cat[256];
  cat[d] = LOCAL[b * 128 + d];
  cat[128 + d] = g;
  __syncthreads();
  float acc = btr[d];
  for (int dd = 0; dd < 256; dd++) acc += cat[dd] * Wtr[(size_t)dd * 128 + d];
  GHT[b * 128 + d] = acc;
}

// ---------------- logits = relu(GHT[256,128] @ item_emb[100000,128]^T) ----------------
__global__ __launch_bounds__(256) void logits_kernel(
    const float* __restrict__ GHT, const float* __restrict__ item_emb,
    float* __restrict__ out) {
  int n = blockIdx.x * 256 + threadIdx.x;
  int m0 = blockIdx.y * 32;
  if (n >= NB_NITEMS) return;
  float acc[32];
#pragma unroll
  for (int i = 0; i < 32; i++) acc[i] = 0.f;
  for (int d0 = 0; d0 < 128; d0 += 8) {
    float e[8];
#pragma unroll
    for (int dd = 0; dd < 8; dd++) e[dd] = item_emb[(size_t)n * 128 + d0 + dd];
#pragma unroll
    for (int i = 0; i < 32; i++) {
      const float* g = GHT + (size_t)(m0 + i) * 128 + d0;  // uniform -> s_load
#pragma unroll
      for (int dd = 0; dd < 8; dd++) acc[i] += g[dd] * e[dd];
    }
  }
#pragma unroll
  for (int i = 0; i < 32; i++)
    out[(size_t)(m0 + i) * NB_NITEMS + n] = fmaxf(acc[i], 0.f);
}

extern "C" void kernel_launch(void* const* d_in, const int* in_sizes, int n_in,
                              void* d_out, int out_size, void* d_ws, size_t ws_size,
                              hipStream_t stream) {
  const int* h_iids = (const int*)d_in[0];
  const int* adj_e = (const int*)d_in[2];
  const int* adj_r = (const int*)d_in[3];
  const float* item_emb = (const float*)d_in[4];
  const float* rel_emb = (const float*)d_in[5];
  const float* Wa = (const float*)d_in[6];
  const float* Wt = (const float*)d_in[8];
  const float* bt = (const float*)d_in[9];
  const float* Wih = (const float*)d_in[10];
  const float* Whh = (const float*)d_in[11];
  const float* bih = (const float*)d_in[12];
  const float* bhh = (const float*)d_in[13];
  const float* W1 = (const float*)d_in[14];
  const float* b1 = (const float*)d_in[15];
  const float* W2 = (const float*)d_in[16];
  const float* b2 = (const float*)d_in[17];
  const float* W3 = (const float*)d_in[18];
  const float* Wtr = (const float*)d_in[19];
  const float* btr = (const float*)d_in[20];
  float* out = (float*)d_out;

  // workspace layout (floats): total ~21.4M floats = 85.6 MB
  float* ws = (float*)d_ws;
  float* BUF0 = ws;                               // 102400*128 (X0 -> NEIB1 in place)
  float* X1 = BUF0 + (size_t)102400 * 128;        // 12800*128 (X1 -> SEQ in place)
  float* GI = X1 + (size_t)12800 * 128;           // 12800*384
  float* GOUT = GI + (size_t)12800 * 384;         // 12800*128
  float* LOCAL = GOUT + (size_t)12800 * 128;      // 256*128
  float* Q1 = LOCAL + 256 * 128;                  // 256*128
  float* AL = Q1 + 256 * 128;                     // 12800
  float* GHT = AL + 12800;                        // 256*128

  // hop0: 102400 pairs, 4 waves/block
  hop_x_kernel<0><<<102400 / 4, 256, 0, stream>>>(h_iids, adj_e, adj_r, item_emb,
                                                  rel_emb, nullptr, Wa, BUF0, 102400);
  // NEIB1 = X0 @ Wt + bt (in place)
  lin_kernel<128, 8><<<102400 / 32, 256, 0, stream>>>(BUF0, Wt, bt, BUF0, 102400);
  // hop1: 12800 pairs
  hop_x_kernel<1><<<12800 / 4, 256, 0, stream>>>(h_iids, adj_e, adj_r, item_emb,
                                                 rel_emb, BUF0, Wa, X1, 12800);
  // SEQ = X1 @ Wt + bt (in place)
  lin_kernel<128, 8><<<12800 / 32, 256, 0, stream>>>(X1, Wt, bt, X1, 12800);
  // GI = SEQ @ Wih + bih
  lin_kernel<384, 4><<<12800 / 16, 256, 0, stream>>>(X1, Wih, bih, GI, 12800);
  // GRU recurrence
  gru_kernel<<<256, 384, 0, stream>>>(GI, Whh, bhh, GOUT);
  // pooling
  pool_a_kernel<<<256, 128, 0, stream>>>(h_iids, GOUT, W1, b1, LOCAL, Q1);
  pool_b_kernel<<<12800 / 4, 256, 0, stream>>>(GOUT, W2, b2, W3, Q1, AL);
  pool_c_kernel<<<256, 128, 0, stream>>>(GOUT, AL, LOCAL, Wtr, btr, GHT);
  // logits
  dim3 lg((NB_NITEMS + 255) / 256, 8);
  logits_kernel<<<lg, 256, 0, stream>>>(GHT, item_emb, out);
}

// Round 2
// 448.896 us; speedup vs baseline: 1.1753x; 1.1753x over previous
//
#include <hip/hip_runtime.h>
#include <hip/hip_bf16.h>
#include <math.h>

#define NB_B 256
#define NB_S 50
#define NB_NB 8
#define NB_D 128
#define NB_NITEMS 100000

__device__ __forceinline__ float wave_sum(float t) {
#pragma unroll
  for (int off = 32; off; off >>= 1) t += __shfl_xor(t, off);
  return t;
}

__device__ __forceinline__ float sigf(float x) { return 1.f / (1.f + __expf(-x)); }

// ---------------- hop aggregation: X = self + sum_k alpha_k * nb_k ----------------
template <int LEVEL>
__global__ __launch_bounds__(256) void hop_x_kernel(
    const int* __restrict__ h_iids, const int* __restrict__ adj_e,
    const int* __restrict__ adj_r, const float* __restrict__ item_emb,
    const float* __restrict__ rel_emb, const float* __restrict__ neib,
    const float* __restrict__ Wa, float* __restrict__ Xout, int npairs) {
  int p = (int)((blockIdx.x * blockDim.x + threadIdx.x) >> 6);
  p = __builtin_amdgcn_readfirstlane(p);
  int ln = threadIdx.x & 63;
  if (p >= npairs) return;

  int e_self;
  if (LEVEL == 0) {
    int b = p / (NB_S * NB_NB);
    int m = p % (NB_S * NB_NB);
    int s = m >> 3, j = m & 7;
    int h = h_iids[b * NB_S + s];
    e_self = adj_e[h * NB_NB + j];
  } else {
    e_self = h_iids[p];  // p = b*S + s
  }

  float wa0 = Wa[ln], wa1 = Wa[64 + ln];
  const float* selfp = item_emb + (size_t)e_self * NB_D;
  float s0 = selfp[ln], s1 = selfp[64 + ln];

  float nb0[NB_NB], nb1[NB_NB], att[NB_NB];
#pragma unroll
  for (int k = 0; k < NB_NB; k++) {
    int r = adj_r[e_self * NB_NB + k];
    const float* nbp;
    if (LEVEL == 0) {
      int e2 = adj_e[e_self * NB_NB + k];
      nbp = item_emb + (size_t)e2 * NB_D;
    } else {
      nbp = neib + ((size_t)p * NB_NB + k) * NB_D;
    }
    nb0[k] = nbp[ln];
    nb1[k] = nbp[64 + ln];
    const float* rp = rel_emb + (size_t)r * NB_D;
    float t = s0 * rp[ln] * nb0[k] * wa0 + s1 * rp[64 + ln] * nb1[k] * wa1;
    att[k] = wave_sum(t);  // +ba omitted: softmax-invariant constant
  }
  float mx = att[0];
#pragma unroll
  for (int k = 1; k < NB_NB; k++) mx = fmaxf(mx, att[k]);
  float den = 0.f, ex[NB_NB];
#pragma unroll
  for (int k = 0; k < NB_NB; k++) { ex[k] = __expf(att[k] - mx); den += ex[k]; }
  float inv = 1.f / den;
  float x0 = s0, x1 = s1;
#pragma unroll
  for (int k = 0; k < NB_NB; k++) {
    float a = ex[k] * inv;
    x0 += a * nb0[k];
    x1 += a * nb1[k];
  }
  float* o = Xout + (size_t)p * NB_D;
  o[ln] = x0;
  o[64 + ln] = x1;
}

// ---------------- generic Y[N,CO] = X[N,128] @ W[128,CO] + bias ----------------
template <int CO, int RPW>
__global__ __launch_bounds__(256) void lin_kernel(const float* X,
                                                  const float* __restrict__ W,
                                                  const float* __restrict__ bias,
                                                  float* Y, int nrows) {
  constexpr int Q = CO / 64;
  int wave = (int)(blockIdx.x * 4 + (threadIdx.x >> 6));
  int ln = threadIdx.x & 63;
  int row0 = __builtin_amdgcn_readfirstlane(wave) * RPW;
  if (row0 >= nrows) return;

  float acc[RPW][Q];
#pragma unroll
  for (int r = 0; r < RPW; r++)
#pragma unroll
    for (int q = 0; q < Q; q++) acc[r][q] = 0.f;

  for (int d0 = 0; d0 < 128; d0 += 4) {
    float xv[RPW][4];
#pragma unroll
    for (int r = 0; r < RPW; r++)
#pragma unroll
      for (int dd = 0; dd < 4; dd++)
        xv[r][dd] = X[(size_t)(row0 + r) * 128 + d0 + dd];  // uniform -> s_load
#pragma unroll
    for (int dd = 0; dd < 4; dd++) {
      float w[Q];
#pragma unroll
      for (int q = 0; q < Q; q++) w[q] = W[(size_t)(d0 + dd) * CO + q * 64 + ln];
#pragma unroll
      for (int r = 0; r < RPW; r++)
#pragma unroll
        for (int q = 0; q < Q; q++) acc[r][q] += xv[r][dd] * w[q];
    }
  }
#pragma unroll
  for (int q = 0; q < Q; q++) {
    float bv = bias[q * 64 + ln];
#pragma unroll
    for (int r = 0; r < RPW; r++)
      Y[(size_t)(row0 + r) * CO + q * 64 + ln] = acc[r][q] + bv;
  }
}

// ---------------- GRU ----------------
__global__ __launch_bounds__(384) void gru_kernel(const float* __restrict__ GI,
                                                  const float* __restrict__ Whh,
                                                  const float* __restrict__ bhh,
                                                  float* __restrict__ OUT) {
  int b = blockIdx.x;
  int j = threadIdx.x;  // 0..383
  __shared__ float h_s[128];
  __shared__ float gh_s[384];

  float wcol[128];
#pragma unroll
  for (int d = 0; d < 128; d++) wcol[d] = Whh[(size_t)d * 384 + j];
  float bh = bhh[j];
  if (j < 128) h_s[j] = 0.f;
  __syncthreads();

  for (int t = 0; t < NB_S; t++) {
    float gh = bh;
    const float4* h4 = (const float4*)h_s;
#pragma unroll
    for (int d4 = 0; d4 < 32; d4++) {
      float4 hv = h4[d4];
      gh += hv.x * wcol[4 * d4] + hv.y * wcol[4 * d4 + 1] +
            hv.z * wcol[4 * d4 + 2] + hv.w * wcol[4 * d4 + 3];
    }
    gh_s[j] = gh;
    __syncthreads();
    if (j < 128) {
      const float* gi = GI + ((size_t)b * NB_S + t) * 384;
      float r = sigf(gi[j] + gh_s[j]);
      float z = sigf(gi[128 + j] + gh_s[128 + j]);
      float n = tanhf(gi[256 + j] + r * gh_s[256 + j]);
      float h2 = (1.f - z) * n + z * h_s[j];
      OUT[((size_t)b * NB_S + t) * 128 + j] = h2;
      h_s[j] = h2;
    }
    __syncthreads();
  }
}

// ---------------- pooling ----------------
__global__ __launch_bounds__(128) void pool_a_kernel(
    const int* __restrict__ h_iids, const float* __restrict__ OUT,
    const float* __restrict__ W1, const float* __restrict__ b1,
    float* __restrict__ LOCAL, float* __restrict__ Q1) {
  int b = blockIdx.x, c = threadIdx.x;
  int cnt = 0;
  for (int s = 0; s < NB_S; s++) cnt += (h_iids[b * NB_S + s] != 0);
  int li = min(max(cnt - 1, 0), NB_S - 1);
  __shared__ float lh[128];
  float lv = OUT[((size_t)b * NB_S + li) * 128 + c];
  lh[c] = lv;
  LOCAL[b * 128 + c] = lv;
  __syncthreads();
  float acc = b1[c];
  for (int d = 0; d < 128; d++) acc += lh[d] * W1[(size_t)d * 128 + c];
  Q1[b * 128 + c] = acc;
}

__global__ __launch_bounds__(256) void pool_b_kernel(
    const float* __restrict__ OUT, const float* __restrict__ W2,
    const float* __restrict__ b2, const float* __restrict__ W3,
    const float* __restrict__ Q1, float* __restrict__ AL) {
  int p = (int)((blockIdx.x * blockDim.x + threadIdx.x) >> 6);
  p = __builtin_amdgcn_readfirstlane(p);
  int ln = threadIdx.x & 63;
  if (p >= NB_B * NB_S) return;
  int b = p / NB_S;
  const float* x = OUT + (size_t)p * 128;
  float acc0 = b2[ln], acc1 = b2[64 + ln];
  for (int d = 0; d < 128; d++) {
    float xv = x[d];
    acc0 += xv * W2[(size_t)d * 128 + ln];
    acc1 += xv * W2[(size_t)d * 128 + 64 + ln];
  }
  float t = sigf(Q1[b * 128 + ln] + acc0) * W3[ln] +
            sigf(Q1[b * 128 + 64 + ln] + acc1) * W3[64 + ln];
  t = wave_sum(t);
  if (ln == 0) AL[p] = t;
}

__global__ __launch_bounds__(128) void pool_c_kernel(
    const float* __restrict__ OUT, const float* __restrict__ AL,
    const float* __restrict__ LOCAL, const float* __restrict__ Wtr,
    const float* __restrict__ btr, float* __restrict__ GHT) {
  int b = blockIdx.x, d = threadIdx.x;
  float g = 0.f;
  for (int s = 0; s < NB_S; s++)
    g += AL[b * NB_S + s] * OUT[((size_t)b * NB_S + s) * 128 + d];
  __shared__ float cat[256];
  cat[d] = LOCAL[b * 128 + d];
  cat[128 + d] = g;
  __syncthreads();
  float acc = btr[d];
  for (int dd = 0; dd < 256; dd++) acc += cat[dd] * Wtr[(size_t)dd * 128 + d];
  GHT[b * 128 + d] = acc;
}

// ---------------- logits = relu(GHT[256,128] @ item_emb[100000,128]^T) ----------------
// Register-tiled fp32 GEMM: block covers ALL 256 M rows x 128 items, K chunked
// by 32 through LDS. item_emb is read exactly once from HBM (51.2 MB total).
// 512 threads, 8x8 micro-tile each. LDS = 32KB(A) + 16KB(B) -> 3 blocks/CU.
__global__ __launch_bounds__(512) void logits_gemm_kernel(
    const float* __restrict__ GHT, const float* __restrict__ item_emb,
    float* __restrict__ out) {
  __shared__ float As[32][256];  // [k][m]
  __shared__ float Bs[32][128];  // [k][n]
  const int tid = threadIdx.x;
  const int n0 = blockIdx.x * 128;
  const int tx = tid & 15;   // n: 16 x 8
  const int ty = tid >> 4;   // m: 32 x 8

  float acc[8][8];
#pragma unroll
  for (int i = 0; i < 8; i++)
#pragma unroll
    for (int j = 0; j < 8; j++) acc[i][j] = 0.f;

  for (int kc = 0; kc < 128; kc += 32) {
    // A: 256 m x 32 k = 2048 float4. lane-major in m -> conflict-free LDS writes.
#pragma unroll
    for (int p = 0; p < 4; p++) {
      int f = tid + p * 512;
      int m = f & 255, k4 = f >> 8;  // k4 in 0..7
      float4 v = *(const float4*)&GHT[(size_t)m * 128 + kc + k4 * 4];
      As[k4 * 4 + 0][m] = v.x;
      As[k4 * 4 + 1][m] = v.y;
      As[k4 * 4 + 2][m] = v.z;
      As[k4 * 4 + 3][m] = v.w;
    }
    // B: 128 n x 32 k = 1024 float4, lane-major in n.
#pragma unroll
    for (int p = 0; p < 2; p++) {
      int f = tid + p * 512;
      int n = f & 127, k4 = f >> 7;  // k4 in 0..7
      int gn = n0 + n;
      float4 v = make_float4(0.f, 0.f, 0.f, 0.f);
      if (gn < NB_NITEMS) v = *(const float4*)&item_emb[(size_t)gn * 128 + kc + k4 * 4];
      Bs[k4 * 4 + 0][n] = v.x;
      Bs[k4 * 4 + 1][n] = v.y;
      Bs[k4 * 4 + 2][n] = v.z;
      Bs[k4 * 4 + 3][n] = v.w;
    }
    __syncthreads();
#pragma unroll
    for (int k = 0; k < 32; k++) {
      float a[8], b[8];
      *(float4*)&a[0] = *(const float4*)&As[k][ty * 8];
      *(float4*)&a[4] = *(const float4*)&As[k][ty * 8 + 4];
      *(float4*)&b[0] = *(const float4*)&Bs[k][tx * 8];
      *(float4*)&b[4] = *(const float4*)&Bs[k][tx * 8 + 4];
#pragma unroll
      for (int i = 0; i < 8; i++)
#pragma unroll
        for (int j = 0; j < 8; j++) acc[i][j] += a[i] * b[j];
    }
    __syncthreads();
  }
#pragma unroll
  for (int i = 0; i < 8; i++) {
    int m = ty * 8 + i;
#pragma unroll
    for (int j4 = 0; j4 < 2; j4++) {
      int n = n0 + tx * 8 + j4 * 4;
      if (n < NB_NITEMS) {  // n and NB_NITEMS both %4==0 -> whole float4 in/out
        float4 v;
        v.x = fmaxf(acc[i][j4 * 4 + 0], 0.f);
        v.y = fmaxf(acc[i][j4 * 4 + 1], 0.f);
        v.z = fmaxf(acc[i][j4 * 4 + 2], 0.f);
        v.w = fmaxf(acc[i][j4 * 4 + 3], 0.f);
        *(float4*)&out[(size_t)m * NB_NITEMS + n] = v;
      }
    }
  }
}

extern "C" void kernel_launch(void* const* d_in, const int* in_sizes, int n_in,
                              void* d_out, int out_size, void* d_ws, size_t ws_size,
                              hipStream_t stream) {
  const int* h_iids = (const int*)d_in[0];
  const int* adj_e = (const int*)d_in[2];
  const int* adj_r = (const int*)d_in[3];
  const float* item_emb = (const float*)d_in[4];
  const float* rel_emb = (const float*)d_in[5];
  const float* Wa = (const float*)d_in[6];
  const float* Wt = (const float*)d_in[8];
  const float* bt = (const float*)d_in[9];
  const float* Wih = (const float*)d_in[10];
  const float* Whh = (const float*)d_in[11];
  const float* bih = (const float*)d_in[12];
  const float* bhh = (const float*)d_in[13];
  const float* W1 = (const float*)d_in[14];
  const float* b1 = (const float*)d_in[15];
  const float* W2 = (const float*)d_in[16];
  const float* b2 = (const float*)d_in[17];
  const float* W3 = (const float*)d_in[18];
  const float* Wtr = (const float*)d_in[19];
  const float* btr = (const float*)d_in[20];
  float* out = (float*)d_out;

  float* ws = (float*)d_ws;
  float* BUF0 = ws;                               // 102400*128
  float* X1 = BUF0 + (size_t)102400 * 128;        // 12800*128
  float* GI = X1 + (size_t)12800 * 128;           // 12800*384
  float* GOUT = GI + (size_t)12800 * 384;         // 12800*128
  float* LOCAL = GOUT + (size_t)12800 * 128;      // 256*128
  float* Q1 = LOCAL + 256 * 128;                  // 256*128
  float* AL = Q1 + 256 * 128;                     // 12800
  float* GHT = AL + 12800;                        // 256*128

  hop_x_kernel<0><<<102400 / 4, 256, 0, stream>>>(h_iids, adj_e, adj_r, item_emb,
                                                  rel_emb, nullptr, Wa, BUF0, 102400);
  lin_kernel<128, 8><<<102400 / 32, 256, 0, stream>>>(BUF0, Wt, bt, BUF0, 102400);
  hop_x_kernel<1><<<12800 / 4, 256, 0, stream>>>(h_iids, adj_e, adj_r, item_emb,
                                                 rel_emb, BUF0, Wa, X1, 12800);
  lin_kernel<128, 8><<<12800 / 32, 256, 0, stream>>>(X1, Wt, bt, X1, 12800);
  lin_kernel<384, 4><<<12800 / 16, 256, 0, stream>>>(X1, Wih, bih, GI, 12800);
  gru_kernel<<<256, 384, 0, stream>>>(GI, Whh, bhh, GOUT);
  pool_a_kernel<<<256, 128, 0, stream>>>(h_iids, GOUT, W1, b1, LOCAL, Q1);
  pool_b_kernel<<<12800 / 4, 256, 0, stream>>>(GOUT, W2, b2, W3, Q1, AL);
  pool_c_kernel<<<256, 128, 0, stream>>>(GOUT, AL, LOCAL, Wtr, btr, GHT);

  logits_gemm_kernel<<<(NB_NITEMS + 127) / 128, 512, 0, stream>>>(GHT, item_emb, out);
}

// Round 3
// 316.969 us; speedup vs baseline: 1.6645x; 1.4162x over previous
//
#include <hip/hip_runtime.h>
#include <hip/hip_bf16.h>
#include <math.h>

#define NB_B 256
#define NB_S 50
#define NB_NB 8
#define NB_D 128
#define NB_NITEMS 100000

typedef __attribute__((ext_vector_type(8))) short short8;   // 8 x bf16 (4 VGPR)
typedef __attribute__((ext_vector_type(4))) float f32x4;    // MFMA acc

__device__ __forceinline__ float wave_sum(float t) {
#pragma unroll
  for (int off = 32; off; off >>= 1) t += __shfl_xor(t, off);
  return t;
}

__device__ __forceinline__ float sigf(float x) { return 1.f / (1.f + __expf(-x)); }

// fp32 -> bf16 with round-to-nearest-even (bit trick)
__device__ __forceinline__ short f2bf(float f) {
  union { float f; unsigned u; } v;
  v.f = f;
  unsigned r = (v.u + 0x7fffu + ((v.u >> 16) & 1u)) >> 16;
  return (short)r;
}

// ---------------- hop aggregation: X = self + sum_k alpha_k * nb_k ----------------
// LEVEL 0 writes bf16 (feeds MFMA lin0); LEVEL 1 writes fp32.
template <int LEVEL>
__global__ __launch_bounds__(256) void hop_x_kernel(
    const int* __restrict__ h_iids, const int* __restrict__ adj_e,
    const int* __restrict__ adj_r, const float* __restrict__ item_emb,
    const float* __restrict__ rel_emb, const float* __restrict__ neib,
    const float* __restrict__ Wa, float* __restrict__ XoutF,
    unsigned short* __restrict__ XoutB, int npairs) {
  int p = (int)((blockIdx.x * blockDim.x + threadIdx.x) >> 6);
  p = __builtin_amdgcn_readfirstlane(p);
  int ln = threadIdx.x & 63;
  if (p >= npairs) return;

  int e_self;
  if (LEVEL == 0) {
    int b = p / (NB_S * NB_NB);
    int m = p % (NB_S * NB_NB);
    int s = m >> 3, j = m & 7;
    int h = h_iids[b * NB_S + s];
    e_self = adj_e[h * NB_NB + j];
  } else {
    e_self = h_iids[p];  // p = b*S + s
  }

  float wa0 = Wa[ln], wa1 = Wa[64 + ln];
  const float* selfp = item_emb + (size_t)e_self * NB_D;
  float s0 = selfp[ln], s1 = selfp[64 + ln];

  float nb0[NB_NB], nb1[NB_NB], att[NB_NB];
#pragma unroll
  for (int k = 0; k < NB_NB; k++) {
    int r = adj_r[e_self * NB_NB + k];
    const float* nbp;
    if (LEVEL == 0) {
      int e2 = adj_e[e_self * NB_NB + k];
      nbp = item_emb + (size_t)e2 * NB_D;
    } else {
      nbp = neib + ((size_t)p * NB_NB + k) * NB_D;
    }
    nb0[k] = nbp[ln];
    nb1[k] = nbp[64 + ln];
    const float* rp = rel_emb + (size_t)r * NB_D;
    float t = s0 * rp[ln] * nb0[k] * wa0 + s1 * rp[64 + ln] * nb1[k] * wa1;
    att[k] = wave_sum(t);  // +ba omitted: softmax-invariant constant
  }
  float mx = att[0];
#pragma unroll
  for (int k = 1; k < NB_NB; k++) mx = fmaxf(mx, att[k]);
  float den = 0.f, ex[NB_NB];
#pragma unroll
  for (int k = 0; k < NB_NB; k++) { ex[k] = __expf(att[k] - mx); den += ex[k]; }
  float inv = 1.f / den;
  float x0 = s0, x1 = s1;
#pragma unroll
  for (int k = 0; k < NB_NB; k++) {
    float a = ex[k] * inv;
    x0 += a * nb0[k];
    x1 += a * nb1[k];
  }
  if (LEVEL == 0) {
    unsigned short* o = XoutB + (size_t)p * NB_D;
    o[ln] = (unsigned short)f2bf(x0);
    o[64 + ln] = (unsigned short)f2bf(x1);
  } else {
    float* o = XoutF + (size_t)p * NB_D;
    o[ln] = x0;
    o[64 + ln] = x1;
  }
}

// ---------------- Wt[128,128] -> WtT_bf16[n][k] ----------------
__global__ __launch_bounds__(256) void cast_wtT_kernel(const float* __restrict__ Wt,
                                                       unsigned short* __restrict__ WtT) {
  int idx = blockIdx.x * 256 + threadIdx.x;  // 16384
  int k = idx >> 7, n = idx & 127;
  WtT[(size_t)n * 128 + k] = (unsigned short)f2bf(Wt[(size_t)k * 128 + n]);
}

// ---------------- NEIB[N,128] = Xbf[N,128] @ WtT_bf^T + bt  (MFMA, no LDS) ----------------
// Wave handles 32 rows x 128 cols. A frag: contiguous 16B from Xbf row.
// B frag: contiguous 16B from WtT (stored [n][k]).
__global__ __launch_bounds__(256) void lin0_mfma_kernel(
    const unsigned short* __restrict__ Xbf, const unsigned short* __restrict__ WtT,
    const float* __restrict__ bt, float* __restrict__ Y, int nrows) {
  int wave = (int)(blockIdx.x * 4 + (threadIdx.x >> 6));
  int ln = threadIdx.x & 63;
  int m0 = __builtin_amdgcn_readfirstlane(wave) * 32;
  if (m0 >= nrows) return;
  int lr = ln & 15, lg = ln >> 4;

  short8 afr[2][4];
#pragma unroll
  for (int mf = 0; mf < 2; mf++) {
    const unsigned short* ab = Xbf + (size_t)(m0 + mf * 16 + lr) * 128 + lg * 8;
#pragma unroll
    for (int kf = 0; kf < 4; kf++) afr[mf][kf] = *(const short8*)(ab + kf * 32);
  }
  f32x4 acc[2][8] = {};
#pragma unroll
  for (int nf = 0; nf < 8; nf++) {
    const unsigned short* bb = WtT + (size_t)(nf * 16 + lr) * 128 + lg * 8;
#pragma unroll
    for (int kf = 0; kf < 4; kf++) {
      short8 b = *(const short8*)(bb + kf * 32);
#pragma unroll
      for (int mf = 0; mf < 2; mf++)
        acc[mf][nf] = __builtin_amdgcn_mfma_f32_16x16x32_bf16(afr[mf][kf], b,
                                                              acc[mf][nf], 0, 0, 0);
    }
  }
#pragma unroll
  for (int mf = 0; mf < 2; mf++)
#pragma unroll
    for (int nf = 0; nf < 8; nf++) {
      int n = nf * 16 + lr;
      float bv = bt[n];
#pragma unroll
      for (int r = 0; r < 4; r++) {
        int m = m0 + mf * 16 + lg * 4 + r;
        Y[(size_t)m * 128 + n] = acc[mf][nf][r] + bv;
      }
    }
}

// ---------------- generic Y[N,CO] = X[N,128] @ W[128,CO] + bias (fp32) ----------------
template <int CO, int RPW>
__global__ __launch_bounds__(256) void lin_kernel(const float* X,
                                                  const float* __restrict__ W,
                                                  const float* __restrict__ bias,
                                                  float* Y, int nrows) {
  constexpr int Q = CO / 64;
  int wave = (int)(blockIdx.x * 4 + (threadIdx.x >> 6));
  int ln = threadIdx.x & 63;
  int row0 = __builtin_amdgcn_readfirstlane(wave) * RPW;
  if (row0 >= nrows) return;

  float acc[RPW][Q];
#pragma unroll
  for (int r = 0; r < RPW; r++)
#pragma unroll
    for (int q = 0; q < Q; q++) acc[r][q] = 0.f;

  for (int d0 = 0; d0 < 128; d0 += 4) {
    float xv[RPW][4];
#pragma unroll
    for (int r = 0; r < RPW; r++)
#pragma unroll
      for (int dd = 0; dd < 4; dd++)
        xv[r][dd] = X[(size_t)(row0 + r) * 128 + d0 + dd];  // uniform -> s_load
#pragma unroll
    for (int dd = 0; dd < 4; dd++) {
      float w[Q];
#pragma unroll
      for (int q = 0; q < Q; q++) w[q] = W[(size_t)(d0 + dd) * CO + q * 64 + ln];
#pragma unroll
      for (int r = 0; r < RPW; r++)
#pragma unroll
        for (int q = 0; q < Q; q++) acc[r][q] += xv[r][dd] * w[q];
    }
  }
#pragma unroll
  for (int q = 0; q < Q; q++) {
    float bv = bias[q * 64 + ln];
#pragma unroll
    for (int r = 0; r < RPW; r++)
      Y[(size_t)(row0 + r) * CO + q * 64 + ln] = acc[r][q] + bv;
  }
}

// ---------------- GRU ----------------
__global__ __launch_bounds__(384) void gru_kernel(const float* __restrict__ GI,
                                                  const float* __restrict__ Whh,
                                                  const float* __restrict__ bhh,
                                                  float* __restrict__ OUT) {
  int b = blockIdx.x;
  int j = threadIdx.x;  // 0..383
  __shared__ float h_s[128];
  __shared__ float gh_s[384];

  float wcol[128];
#pragma unroll
  for (int d = 0; d < 128; d++) wcol[d] = Whh[(size_t)d * 384 + j];
  float bh = bhh[j];
  if (j < 128) h_s[j] = 0.f;
  __syncthreads();

  for (int t = 0; t < NB_S; t++) {
    float gh = bh;
    const float4* h4 = (const float4*)h_s;
#pragma unroll
    for (int d4 = 0; d4 < 32; d4++) {
      float4 hv = h4[d4];
      gh += hv.x * wcol[4 * d4] + hv.y * wcol[4 * d4 + 1] +
            hv.z * wcol[4 * d4 + 2] + hv.w * wcol[4 * d4 + 3];
    }
    gh_s[j] = gh;
    __syncthreads();
    if (j < 128) {
      const float* gi = GI + ((size_t)b * NB_S + t) * 384;
      float r = sigf(gi[j] + gh_s[j]);
      float z = sigf(gi[128 + j] + gh_s[128 + j]);
      float n = tanhf(gi[256 + j] + r * gh_s[256 + j]);
      float h2 = (1.f - z) * n + z * h_s[j];
      OUT[((size_t)b * NB_S + t) * 128 + j] = h2;
      h_s[j] = h2;
    }
    __syncthreads();
  }
}

// ---------------- pooling ----------------
__global__ __launch_bounds__(128) void pool_a_kernel(
    const int* __restrict__ h_iids, const float* __restrict__ OUT,
    const float* __restrict__ W1, const float* __restrict__ b1,
    float* __restrict__ LOCAL, float* __restrict__ Q1) {
  int b = blockIdx.x, c = threadIdx.x;
  int cnt = 0;
  for (int s = 0; s < NB_S; s++) cnt += (h_iids[b * NB_S + s] != 0);
  int li = min(max(cnt - 1, 0), NB_S - 1);
  __shared__ float lh[128];
  float lv = OUT[((size_t)b * NB_S + li) * 128 + c];
  lh[c] = lv;
  LOCAL[b * 128 + c] = lv;
  __syncthreads();
  float acc = b1[c];
  for (int d = 0; d < 128; d++) acc += lh[d] * W1[(size_t)d * 128 + c];
  Q1[b * 128 + c] = acc;
}

__global__ __launch_bounds__(256) void pool_b_kernel(
    const float* __restrict__ OUT, const float* __restrict__ W2,
    const float* __restrict__ b2, const float* __restrict__ W3,
    const float* __restrict__ Q1, float* __restrict__ AL) {
  int p = (int)((blockIdx.x * blockDim.x + threadIdx.x) >> 6);
  p = __builtin_amdgcn_readfirstlane(p);
  int ln = threadIdx.x & 63;
  if (p >= NB_B * NB_S) return;
  int b = p / NB_S;
  const float* x = OUT + (size_t)p * 128;
  float acc0 = b2[ln], acc1 = b2[64 + ln];
  for (int d = 0; d < 128; d++) {
    float xv = x[d];
    acc0 += xv * W2[(size_t)d * 128 + ln];
    acc1 += xv * W2[(size_t)d * 128 + 64 + ln];
  }
  float t = sigf(Q1[b * 128 + ln] + acc0) * W3[ln] +
            sigf(Q1[b * 128 + 64 + ln] + acc1) * W3[64 + ln];
  t = wave_sum(t);
  if (ln == 0) AL[p] = t;
}

__global__ __launch_bounds__(128) void pool_c_kernel(
    const float* __restrict__ OUT, const float* __restrict__ AL,
    const float* __restrict__ LOCAL, const float* __restrict__ Wtr,
    const float* __restrict__ btr, unsigned short* __restrict__ GHT_bf) {
  int b = blockIdx.x, d = threadIdx.x;
  float g = 0.f;
  for (int s = 0; s < NB_S; s++)
    g += AL[b * NB_S + s] * OUT[((size_t)b * NB_S + s) * 128 + d];
  __shared__ float cat[256];
  cat[d] = LOCAL[b * 128 + d];
  cat[128 + d] = g;
  __syncthreads();
  float acc = btr[d];
  for (int dd = 0; dd < 256; dd++) acc += cat[dd] * Wtr[(size_t)dd * 128 + d];
  GHT_bf[b * 128 + d] = (unsigned short)f2bf(acc);
}

// ---------------- logits = relu(GHT[256,128] @ item_emb[100000,128]^T) via MFMA ----------------
// Wave: all 256 m-rows x 32 items. B frags converted fp32->bf16 in-flight
// (each emb row touched by exactly one wave). No LDS, no barriers.
__global__ __launch_bounds__(256) void logits_mfma_kernel(
    const unsigned short* __restrict__ GHT_bf, const float* __restrict__ item_emb,
    float* __restrict__ out) {
  int wave = (int)(blockIdx.x * 4 + (threadIdx.x >> 6));
  int ln = threadIdx.x & 63;
  int n0 = __builtin_amdgcn_readfirstlane(wave) * 32;
  if (n0 >= NB_NITEMS) return;
  int lr = ln & 15, lg = ln >> 4;

  short8 bfr[2][4];
#pragma unroll
  for (int nf = 0; nf < 2; nf++) {
    const float* base = item_emb + (size_t)(n0 + nf * 16 + lr) * 128 + lg * 8;
#pragma unroll
    for (int kf = 0; kf < 4; kf++) {
      float4 e0 = *(const float4*)(base + kf * 32);
      float4 e1 = *(const float4*)(base + kf * 32 + 4);
      short8 t;
      t[0] = f2bf(e0.x); t[1] = f2bf(e0.y); t[2] = f2bf(e0.z); t[3] = f2bf(e0.w);
      t[4] = f2bf(e1.x); t[5] = f2bf(e1.y); t[6] = f2bf(e1.z); t[7] = f2bf(e1.w);
      bfr[nf][kf] = t;
    }
  }

  f32x4 acc[16][2] = {};
#pragma unroll
  for (int mg = 0; mg < 4; mg++) {
    short8 afr[4][4];
#pragma unroll
    for (int mf = 0; mf < 4; mf++) {
      const unsigned short* ab = GHT_bf + (size_t)((mg * 4 + mf) * 16 + lr) * 128 + lg * 8;
#pragma unroll
      for (int kf = 0; kf < 4; kf++) afr[mf][kf] = *(const short8*)(ab + kf * 32);
    }
#pragma unroll
    for (int mf = 0; mf < 4; mf++)
#pragma unroll
      for (int nf = 0; nf < 2; nf++)
#pragma unroll
        for (int kf = 0; kf < 4; kf++)
          acc[mg * 4 + mf][nf] = __builtin_amdgcn_mfma_f32_16x16x32_bf16(
              afr[mf][kf], bfr[nf][kf], acc[mg * 4 + mf][nf], 0, 0, 0);
  }

#pragma unroll
  for (int mf = 0; mf < 16; mf++)
#pragma unroll
    for (int nf = 0; nf < 2; nf++) {
      int n = n0 + nf * 16 + lr;
#pragma unroll
      for (int r = 0; r < 4; r++) {
        int m = mf * 16 + lg * 4 + r;
        out[(size_t)m * NB_NITEMS + n] = fmaxf(acc[mf][nf][r], 0.f);
      }
    }
}

extern "C" void kernel_launch(void* const* d_in, const int* in_sizes, int n_in,
                              void* d_out, int out_size, void* d_ws, size_t ws_size,
                              hipStream_t stream) {
  const int* h_iids = (const int*)d_in[0];
  const int* adj_e = (const int*)d_in[2];
  const int* adj_r = (const int*)d_in[3];
  const float* item_emb = (const float*)d_in[4];
  const float* rel_emb = (const float*)d_in[5];
  const float* Wa = (const float*)d_in[6];
  const float* Wt = (const float*)d_in[8];
  const float* bt = (const float*)d_in[9];
  const float* Wih = (const float*)d_in[10];
  const float* Whh = (const float*)d_in[11];
  const float* bih = (const float*)d_in[12];
  const float* bhh = (const float*)d_in[13];
  const float* W1 = (const float*)d_in[14];
  const float* b1 = (const float*)d_in[15];
  const float* W2 = (const float*)d_in[16];
  const float* b2 = (const float*)d_in[17];
  const float* W3 = (const float*)d_in[18];
  const float* Wtr = (const float*)d_in[19];
  const float* btr = (const float*)d_in[20];
  float* out = (float*)d_out;

  // ws layout (floats) — ~85.8 MB total, same footprint as R2:
  float* ws = (float*)d_ws;
  float* NEIB = ws;                               // 102400*128 fp32
  float* X1 = NEIB + (size_t)102400 * 128;        // 12800*128
  float* GI = X1 + (size_t)12800 * 128;           // 12800*384
  float* GOUT = GI + (size_t)12800 * 384;         // 12800*128
  float* LOCAL = GOUT + (size_t)12800 * 128;      // 256*128
  float* Q1 = LOCAL + 256 * 128;                  // 256*128
  float* AL = Q1 + 256 * 128;                     // 12800
  unsigned short* GHT_bf = (unsigned short*)(AL + 12800);       // 256*128 bf16
  unsigned short* WtT_bf = GHT_bf + 256 * 128;                  // 128*128 bf16

  // X0 (bf16, 26.2MB) lives in d_out scratch space (102.4MB); logits fully
  // overwrites d_out at the end, so this is poison/replay-safe.
  unsigned short* X0_bf = (unsigned short*)d_out;

  cast_wtT_kernel<<<64, 256, 0, stream>>>(Wt, WtT_bf);
  hop_x_kernel<0><<<102400 / 4, 256, 0, stream>>>(h_iids, adj_e, adj_r, item_emb,
                                                  rel_emb, nullptr, Wa, nullptr,
                                                  X0_bf, 102400);
  lin0_mfma_kernel<<<102400 / 128, 256, 0, stream>>>(X0_bf, WtT_bf, bt, NEIB, 102400);
  hop_x_kernel<1><<<12800 / 4, 256, 0, stream>>>(h_iids, adj_e, adj_r, item_emb,
                                                 rel_emb, NEIB, Wa, X1, nullptr, 12800);
  lin_kernel<128, 8><<<12800 / 32, 256, 0, stream>>>(X1, Wt, bt, X1, 12800);
  lin_kernel<384, 4><<<12800 / 16, 256, 0, stream>>>(X1, Wih, bih, GI, 12800);
  gru_kernel<<<256, 384, 0, stream>>>(GI, Whh, bhh, GOUT);
  pool_a_kernel<<<256, 128, 0, stream>>>(h_iids, GOUT, W1, b1, LOCAL, Q1);
  pool_b_kernel<<<12800 / 4, 256, 0, stream>>>(GOUT, W2, b2, W3, Q1, AL);
  pool_c_kernel<<<256, 128, 0, stream>>>(GOUT, AL, LOCAL, Wtr, btr, GHT_bf);

  logits_mfma_kernel<<<(NB_NITEMS / 32 + 3) / 4, 256, 0, stream>>>(GHT_bf, item_emb, out);
}

// Round 4
// 299.284 us; speedup vs baseline: 1.7628x; 1.0591x over previous
//
#include <hip/hip_runtime.h>
#include <hip/hip_bf16.h>
#include <math.h>

#define NB_B 256
#define NB_S 50
#define NB_NB 8
#define NB_D 128
#define NB_NITEMS 100000

typedef __attribute__((ext_vector_type(8))) short short8;   // 8 x bf16 (4 VGPR)
typedef __attribute__((ext_vector_type(4))) float f32x4;    // MFMA acc
typedef unsigned int uint;
typedef unsigned short ushort;

__device__ __forceinline__ float wave_sum(float t) {
#pragma unroll
  for (int off = 32; off; off >>= 1) t += __shfl_xor(t, off);
  return t;
}

__device__ __forceinline__ float sigf(float x) { return 1.f / (1.f + __expf(-x)); }

// fp32 -> bf16 round-to-nearest-even
__device__ __forceinline__ ushort f2bf(float f) {
  union { float f; uint u; } v;
  v.f = f;
  return (ushort)((v.u + 0x7fffu + ((v.u >> 16) & 1u)) >> 16);
}
__device__ __forceinline__ uint packbf(float a, float b) {
  return (uint)f2bf(a) | ((uint)f2bf(b) << 16);
}
__device__ __forceinline__ float bflo(uint u) {
  union { uint u; float f; } v; v.u = u << 16; return v.f;
}
__device__ __forceinline__ float bfhi(uint u) {
  union { uint u; float f; } v; v.u = u & 0xffff0000u; return v.f;
}

// ---------------- elementwise fp32 -> packed bf16 (8 floats / thread) ----------------
__global__ __launch_bounds__(256) void castf_kernel(const float* __restrict__ src,
                                                    uint* __restrict__ dst, int n8) {
  int i = blockIdx.x * 256 + threadIdx.x;
  if (i >= n8) return;
  float4 a = ((const float4*)src)[2 * i];
  float4 b = ((const float4*)src)[2 * i + 1];
  uint4 o;
  o.x = packbf(a.x, a.y);
  o.y = packbf(a.z, a.w);
  o.z = packbf(b.x, b.y);
  o.w = packbf(b.z, b.w);
  ((uint4*)dst)[i] = o;
}

// ---------------- W[K][CO] -> WT bf16 [CO][K] ----------------
template <int K, int CO>
__global__ __launch_bounds__(256) void castT_kernel(const float* __restrict__ W,
                                                    ushort* __restrict__ WT) {
  int idx = blockIdx.x * 256 + threadIdx.x;
  if (idx >= K * CO) return;
  int n = idx / K, k = idx % K;
  WT[idx] = f2bf(W[(size_t)k * CO + n]);
}

// ---------------- Whh[128][384] -> WhhT fp32 [384][128] ----------------
__global__ __launch_bounds__(256) void transposef_kernel(const float* __restrict__ W,
                                                         float* __restrict__ WT) {
  int idx = blockIdx.x * 256 + threadIdx.x;
  if (idx >= 128 * 384) return;
  int j = idx >> 7, d = idx & 127;
  WT[idx] = W[(size_t)d * 384 + j];
}

// ---------------- hop aggregation (bf16 tables, packed pairs) ----------------
// lane handles dims {2ln, 2ln+1}. Output packed bf16.
template <int LEVEL>
__global__ __launch_bounds__(256) void hop_kernel(
    const int* __restrict__ h_iids, const int* __restrict__ adj_e,
    const int* __restrict__ adj_r, const uint* __restrict__ embB,
    const uint* __restrict__ relB, const uint* __restrict__ neibB,
    const float* __restrict__ Wa, uint* __restrict__ Xout, int npairs) {
  int p = (int)((blockIdx.x * blockDim.x + threadIdx.x) >> 6);
  p = __builtin_amdgcn_readfirstlane(p);
  int ln = threadIdx.x & 63;
  if (p >= npairs) return;

  int e_self;
  if (LEVEL == 0) {
    int b = p / (NB_S * NB_NB);
    int m = p % (NB_S * NB_NB);
    int s = m >> 3, j = m & 7;
    int h = h_iids[b * NB_S + s];
    e_self = adj_e[h * NB_NB + j];
  } else {
    e_self = h_iids[p];
  }

  float wa0 = Wa[2 * ln], wa1 = Wa[2 * ln + 1];
  uint us = embB[(size_t)e_self * 64 + ln];
  float s0 = bflo(us), s1 = bfhi(us);

  float nb0[NB_NB], nb1[NB_NB], att[NB_NB];
#pragma unroll
  for (int k = 0; k < NB_NB; k++) {
    int r = adj_r[e_self * NB_NB + k];
    uint un;
    if (LEVEL == 0) {
      int e2 = adj_e[e_self * NB_NB + k];
      un = embB[(size_t)e2 * 64 + ln];
    } else {
      un = neibB[((size_t)p * NB_NB + k) * 64 + ln];
    }
    uint ur = relB[r * 64 + ln];
    nb0[k] = bflo(un);
    nb1[k] = bfhi(un);
    float t = s0 * bflo(ur) * nb0[k] * wa0 + s1 * bfhi(ur) * nb1[k] * wa1;
    att[k] = wave_sum(t);
  }
  // |att| <= ~0.04 -> exp safe without max-subtraction (softmax-invariant)
  float den = 0.f, ex[NB_NB];
#pragma unroll
  for (int k = 0; k < NB_NB; k++) { ex[k] = __expf(att[k]); den += ex[k]; }
  float inv = 1.f / den;
  float x0 = s0, x1 = s1;
#pragma unroll
  for (int k = 0; k < NB_NB; k++) {
    float a = ex[k] * inv;
    x0 += a * nb0[k];
    x1 += a * nb1[k];
  }
  Xout[(size_t)p * 64 + ln] = packbf(x0, x1);
}

// ---------------- Y[N,CO] = Xbf[N,128] @ WT_bf^T + bias  (MFMA, no LDS) ----------------
// Wave: MPW rows x CO cols. OUT_BF selects packed-bf16 vs fp32 output.
template <int CO, int MPW, bool OUT_BF>
__global__ __launch_bounds__(256) void linm_kernel(
    const ushort* __restrict__ Xbf, const ushort* __restrict__ WT,
    const float* __restrict__ bias, float* __restrict__ Yf,
    ushort* __restrict__ Yb, int nrows) {
  constexpr int NF = CO / 16;
  constexpr int MF = MPW / 16;
  int wave = (int)(blockIdx.x * 4 + (threadIdx.x >> 6));
  int ln = threadIdx.x & 63;
  int m0 = __builtin_amdgcn_readfirstlane(wave) * MPW;
  if (m0 >= nrows) return;
  int lr = ln & 15, lg = ln >> 4;

  short8 afr[MF][4];
#pragma unroll
  for (int mf = 0; mf < MF; mf++) {
    const ushort* ab = Xbf + (size_t)(m0 + mf * 16 + lr) * 128 + lg * 8;
#pragma unroll
    for (int kf = 0; kf < 4; kf++) afr[mf][kf] = *(const short8*)(ab + kf * 32);
  }
  f32x4 acc[MF][NF] = {};
#pragma unroll
  for (int nf = 0; nf < NF; nf++) {
    const ushort* bb = WT + (size_t)(nf * 16 + lr) * 128 + lg * 8;
#pragma unroll
    for (int kf = 0; kf < 4; kf++) {
      short8 b = *(const short8*)(bb + kf * 32);
#pragma unroll
      for (int mf = 0; mf < MF; mf++)
        acc[mf][nf] = __builtin_amdgcn_mfma_f32_16x16x32_bf16(afr[mf][kf], b,
                                                              acc[mf][nf], 0, 0, 0);
    }
  }
#pragma unroll
  for (int mf = 0; mf < MF; mf++)
#pragma unroll
    for (int nf = 0; nf < NF; nf++) {
      int n = nf * 16 + lr;
      float bv = bias[n];
#pragma unroll
      for (int r = 0; r < 4; r++) {
        int m = m0 + mf * 16 + lg * 4 + r;
        float val = acc[mf][nf][r] + bv;
        if (OUT_BF)
          Yb[(size_t)m * CO + n] = f2bf(val);
        else
          Yf[(size_t)m * CO + n] = val;
      }
    }
}

// ---------------- GRU: 1 block/batch, WhhT row-contiguous, 4-chain dot ----------------
__global__ __launch_bounds__(384) void gru_kernel(const float* __restrict__ GI,
                                                  const float* __restrict__ WhhT,
                                                  const float* __restrict__ bhh,
                                                  float* __restrict__ OUT) {
  int b = blockIdx.x;
  int j = threadIdx.x;  // 0..383
  __shared__ float h_s[128];
  __shared__ float gh_s[384];

  float wcol[128];
  const float4* wt4 = (const float4*)(WhhT + (size_t)j * 128);
#pragma unroll
  for (int d4 = 0; d4 < 32; d4++) *(float4*)&wcol[4 * d4] = wt4[d4];
  float bh = bhh[j];
  if (j < 128) h_s[j] = 0.f;
  __syncthreads();

  for (int t = 0; t < NB_S; t++) {
    float gi0 = 0.f, gi1 = 0.f, gi2 = 0.f;
    if (j < 128) {  // issue early; latency hidden under the dot product
      const float* gi = GI + ((size_t)b * NB_S + t) * 384;
      gi0 = gi[j]; gi1 = gi[128 + j]; gi2 = gi[256 + j];
    }
    float a0 = 0.f, a1 = 0.f, a2 = 0.f, a3 = 0.f;
    const float4* h4 = (const float4*)h_s;
#pragma unroll
    for (int d4 = 0; d4 < 32; d4++) {
      float4 hv = h4[d4];
      a0 += hv.x * wcol[4 * d4];
      a1 += hv.y * wcol[4 * d4 + 1];
      a2 += hv.z * wcol[4 * d4 + 2];
      a3 += hv.w * wcol[4 * d4 + 3];
    }
    gh_s[j] = (a0 + a1) + (a2 + a3) + bh;
    __syncthreads();
    if (j < 128) {
      float r = sigf(gi0 + gh_s[j]);
      float z = sigf(gi1 + gh_s[128 + j]);
      float x = gi2 + r * gh_s[256 + j];
      float e2 = __expf(2.f * x);
      float n = 1.f - 2.f / (e2 + 1.f);  // tanh(x), robust at +/-inf
      float h2 = (1.f - z) * n + z * h_s[j];
      OUT[((size_t)b * NB_S + t) * 128 + j] = h2;
      h_s[j] = h2;
    }
    __syncthreads();
  }
}

// ---------------- pooling ----------------
__global__ __launch_bounds__(128) void pool_a_kernel(
    const int* __restrict__ h_iids, const float* __restrict__ OUT,
    const float* __restrict__ W1, const float* __restrict__ b1,
    float* __restrict__ LOCAL, float* __restrict__ Q1) {
  int b = blockIdx.x, c = threadIdx.x;
  int cnt = 0;
  for (int s = 0; s < NB_S; s++) cnt += (h_iids[b * NB_S + s] != 0);
  int li = min(max(cnt - 1, 0), NB_S - 1);
  __shared__ float lh[128];
  float lv = OUT[((size_t)b * NB_S + li) * 128 + c];
  lh[c] = lv;
  LOCAL[b * 128 + c] = lv;
  __syncthreads();
  float acc = b1[c];
  for (int d = 0; d < 128; d++) acc += lh[d] * W1[(size_t)d * 128 + c];
  Q1[b * 128 + c] = acc;
}

__global__ __launch_bounds__(256) void pool_b_kernel(
    const float* __restrict__ OUT, const float* __restrict__ W2,
    const float* __restrict__ b2, const float* __restrict__ W3,
    const float* __restrict__ Q1, float* __restrict__ AL) {
  int p = (int)((blockIdx.x * blockDim.x + threadIdx.x) >> 6);
  p = __builtin_amdgcn_readfirstlane(p);
  int ln = threadIdx.x & 63;
  if (p >= NB_B * NB_S) return;
  int b = p / NB_S;
  const float* x = OUT + (size_t)p * 128;
  float acc0 = b2[ln], acc1 = b2[64 + ln];
  for (int d = 0; d < 128; d++) {
    float xv = x[d];
    acc0 += xv * W2[(size_t)d * 128 + ln];
    acc1 += xv * W2[(size_t)d * 128 + 64 + ln];
  }
  float t = sigf(Q1[b * 128 + ln] + acc0) * W3[ln] +
            sigf(Q1[b * 128 + 64 + ln] + acc1) * W3[64 + ln];
  t = wave_sum(t);
  if (ln == 0) AL[p] = t;
}

__global__ __launch_bounds__(128) void pool_c_kernel(
    const float* __restrict__ OUT, const float* __restrict__ AL,
    const float* __restrict__ LOCAL, const float* __restrict__ Wtr,
    const float* __restrict__ btr, ushort* __restrict__ GHT_bf) {
  int b = blockIdx.x, d = threadIdx.x;
  float g = 0.f;
  for (int s = 0; s < NB_S; s++)
    g += AL[b * NB_S + s] * OUT[((size_t)b * NB_S + s) * 128 + d];
  __shared__ float cat[256];
  cat[d] = LOCAL[b * 128 + d];
  cat[128 + d] = g;
  __syncthreads();
  float acc = btr[d];
  for (int dd = 0; dd < 256; dd++) acc += cat[dd] * Wtr[(size_t)dd * 128 + d];
  GHT_bf[b * 128 + d] = f2bf(acc);
}

// ---------------- logits = relu(GHT_bf @ EMB_BF^T) via MFMA ----------------
__global__ __launch_bounds__(256) void logits_mfma_kernel(
    const ushort* __restrict__ GHT_bf, const ushort* __restrict__ embB,
    float* __restrict__ out) {
  int wave = (int)(blockIdx.x * 4 + (threadIdx.x >> 6));
  int ln = threadIdx.x & 63;
  int n0 = __builtin_amdgcn_readfirstlane(wave) * 32;
  if (n0 >= NB_NITEMS) return;
  int lr = ln & 15, lg = ln >> 4;

  short8 bfr[2][4];
#pragma unroll
  for (int nf = 0; nf < 2; nf++) {
    const ushort* base = embB + (size_t)(n0 + nf * 16 + lr) * 128 + lg * 8;
#pragma unroll
    for (int kf = 0; kf < 4; kf++) bfr[nf][kf] = *(const short8*)(base + kf * 32);
  }

  f32x4 acc[16][2] = {};
#pragma unroll
  for (int mg = 0; mg < 4; mg++) {
    short8 afr[4][4];
#pragma unroll
    for (int mf = 0; mf < 4; mf++) {
      const ushort* ab = GHT_bf + (size_t)((mg * 4 + mf) * 16 + lr) * 128 + lg * 8;
#pragma unroll
      for (int kf = 0; kf < 4; kf++) afr[mf][kf] = *(const short8*)(ab + kf * 32);
    }
#pragma unroll
    for (int mf = 0; mf < 4; mf++)
#pragma unroll
      for (int nf = 0; nf < 2; nf++)
#pragma unroll
        for (int kf = 0; kf < 4; kf++)
          acc[mg * 4 + mf][nf] = __builtin_amdgcn_mfma_f32_16x16x32_bf16(
              afr[mf][kf], bfr[nf][kf], acc[mg * 4 + mf][nf], 0, 0, 0);
  }

#pragma unroll
  for (int mf = 0; mf < 16; mf++)
#pragma unroll
    for (int nf = 0; nf < 2; nf++) {
      int n = n0 + nf * 16 + lr;
#pragma unroll
      for (int r = 0; r < 4; r++) {
        int m = mf * 16 + lg * 4 + r;
        out[(size_t)m * NB_NITEMS + n] = fmaxf(acc[mf][nf][r], 0.f);
      }
    }
}

extern "C" void kernel_launch(void* const* d_in, const int* in_sizes, int n_in,
                              void* d_out, int out_size, void* d_ws, size_t ws_size,
                              hipStream_t stream) {
  const int* h_iids = (const int*)d_in[0];
  const int* adj_e = (const int*)d_in[2];
  const int* adj_r = (const int*)d_in[3];
  const float* item_emb = (const float*)d_in[4];
  const float* rel_emb = (const float*)d_in[5];
  const float* Wa = (const float*)d_in[6];
  const float* Wt = (const float*)d_in[8];
  const float* bt = (const float*)d_in[9];
  const float* Wih = (const float*)d_in[10];
  const float* Whh = (const float*)d_in[11];
  const float* bih = (const float*)d_in[12];
  const float* bhh = (const float*)d_in[13];
  const float* W1 = (const float*)d_in[14];
  const float* b1 = (const float*)d_in[15];
  const float* W2 = (const float*)d_in[16];
  const float* b2 = (const float*)d_in[17];
  const float* W3 = (const float*)d_in[18];
  const float* Wtr = (const float*)d_in[19];
  const float* btr = (const float*)d_in[20];
  float* out = (float*)d_out;

  // ws layout (bytes), all 16B-aligned. Total ~85.3 MB (<= proven R2 budget).
  char* w = (char*)d_ws;
  uint* EMB_BF = (uint*)w;                    w += 25600000;  // 100000x128 bf16
  uint* REL_BF = (uint*)w;                    w += 51200;     // 200x128 bf16
  ushort* WtT_bf = (ushort*)w;                w += 32768;     // [128][128]
  ushort* WihT_bf = (ushort*)w;               w += 98304;     // [384][128]
  float* WhhT = (float*)w;                    w += 196608;    // [384][128] fp32
  uint* NEIB_bf = (uint*)w;                   w += 26214400;  // 102400x128 bf16
  uint* X1_bf = (uint*)w;                     w += 3276800;   // 12800x128 bf16
  uint* SEQ_bf = (uint*)w;                    w += 3276800;   // 12800x128 bf16
  float* GI = (float*)w;                      w += 19660800;  // 12800x384 fp32
  float* GOUT = (float*)w;                    w += 6553600;   // 12800x128 fp32
  float* LOCAL = (float*)w;                   w += 131072;
  float* Q1 = (float*)w;                      w += 131072;
  float* AL = (float*)w;                      w += 51200;
  ushort* GHT_bf = (ushort*)w;                w += 65536;

  // X0 (bf16 packed, 26.2MB) borrows d_out (102.4MB); logits fully overwrites it.
  uint* X0_bf = (uint*)d_out;

  // ---- prep casts ----
  castf_kernel<<<6250, 256, 0, stream>>>(item_emb, EMB_BF, 1600000);
  castf_kernel<<<13, 256, 0, stream>>>(rel_emb, REL_BF, 3200);
  castT_kernel<128, 128><<<64, 256, 0, stream>>>(Wt, WtT_bf);
  castT_kernel<128, 384><<<192, 256, 0, stream>>>(Wih, WihT_bf);
  transposef_kernel<<<192, 256, 0, stream>>>(Whh, WhhT);

  // ---- KG hops ----
  hop_kernel<0><<<25600, 256, 0, stream>>>(h_iids, adj_e, adj_r, EMB_BF, REL_BF,
                                           nullptr, Wa, X0_bf, 102400);
  linm_kernel<128, 32, true><<<800, 256, 0, stream>>>(
      (const ushort*)X0_bf, WtT_bf, bt, nullptr, (ushort*)NEIB_bf, 102400);
  hop_kernel<1><<<3200, 256, 0, stream>>>(h_iids, adj_e, adj_r, EMB_BF, REL_BF,
                                          NEIB_bf, Wa, X1_bf, 12800);
  linm_kernel<128, 32, true><<<100, 256, 0, stream>>>(
      (const ushort*)X1_bf, WtT_bf, bt, nullptr, (ushort*)SEQ_bf, 12800);
  linm_kernel<384, 16, false><<<200, 256, 0, stream>>>(
      (const ushort*)SEQ_bf, WihT_bf, bih, GI, nullptr, 12800);

  // ---- GRU + pooling ----
  gru_kernel<<<256, 384, 0, stream>>>(GI, WhhT, bhh, GOUT);
  pool_a_kernel<<<256, 128, 0, stream>>>(h_iids, GOUT, W1, b1, LOCAL, Q1);
  pool_b_kernel<<<3200, 256, 0, stream>>>(GOUT, W2, b2, W3, Q1, AL);
  pool_c_kernel<<<256, 128, 0, stream>>>(GOUT, AL, LOCAL, Wtr, btr, GHT_bf);

  // ---- logits ----
  logits_mfma_kernel<<<782, 256, 0, stream>>>(GHT_bf, (const ushort*)EMB_BF, out);
}